// Round 1
// baseline (156.849 us; speedup 1.0000x reference)
//
#include <hip/hip_runtime.h>

// Lorenz96 RK4, fp32 — DPP layout:
//   2 lanes per row, 20 elements (5 float4) per lane. The circular stencil
//   halo for a 20-element half-row is exactly 3 values, all held by the
//   paired lane (even<->odd): neighbor s[18], s[19], s[0]. Even/odd swap is
//   DPP quad_perm [1,0,3,2] (ctrl 0xB1) — pure VALU, no DS pipe, no LDS,
//   no __syncthreads, all 64 lanes active.
//   Lane l loads float4s [5*tid, 5*tid+5): 80B per lane, wave footprint is
//   a contiguous 20KB block -> L1/L2 merge the per-instruction stride gaps.

#define FORCE 8.0f

__device__ __forceinline__ float dpp_swap1(float x) {
    // quad_perm [1,0,3,2]: every even/odd lane pair swaps. ctrl=0xB1.
    return __int_as_float(
        __builtin_amdgcn_mov_dpp(__float_as_int(x), 0xB1, 0xF, 0xF, true));
}

__global__ __launch_bounds__(256)
void lorenz96_rk4_dpp(const float4* __restrict__ x0,
                      const float* __restrict__ dt_p,
                      float4* __restrict__ out,
                      long nhalf)   // batch*2 half-rows of 20 floats
{
    const long tid = (long)blockIdx.x * blockDim.x + threadIdx.x;
    if (tid >= nhalf) return;       // pairs (2i,2i+1) die together: nhalf even
    const long base = tid * 5;      // float4 index

    const float dt  = dt_p[0];
    const float hdt = 0.5f * dt;

    float x[20];
#pragma unroll
    for (int j = 0; j < 5; ++j) {
        float4 v = x0[base + j];
        x[4*j+0] = v.x; x[4*j+1] = v.y; x[4*j+2] = v.z; x[4*j+3] = v.w;
    }

    float s[20], k[20], a[20];

    // d[i] = (s[i+1] - s[i-2]) * s[i-1] - s[i] + F, circular over the 40-row;
    // indices -2,-1,+20 map to the paired lane's s[18], s[19], s[0].
#define DERIV(S, D)                                                          \
    {                                                                        \
        const float hm2 = dpp_swap1(S[18]);                                  \
        const float hm1 = dpp_swap1(S[19]);                                  \
        const float hp1 = dpp_swap1(S[0]);                                   \
        D[0] = (S[1] - hm2) * hm1 - S[0] + FORCE;                            \
        D[1] = (S[2] - hm1) * S[0] - S[1] + FORCE;                           \
        _Pragma("unroll")                                                    \
        for (int i = 2; i < 19; ++i)                                         \
            D[i] = (S[i+1] - S[i-2]) * S[i-1] - S[i] + FORCE;                \
        D[19] = (hp1 - S[17]) * S[18] - S[19] + FORCE;                       \
    }

    // k1
    DERIV(x, k);
#pragma unroll
    for (int i = 0; i < 20; ++i) { a[i] = k[i];        s[i] = fmaf(hdt, k[i], x[i]); }
    // k2
    DERIV(s, k);
#pragma unroll
    for (int i = 0; i < 20; ++i) { a[i] += 2.0f*k[i];  s[i] = fmaf(hdt, k[i], x[i]); }
    // k3
    DERIV(s, k);
#pragma unroll
    for (int i = 0; i < 20; ++i) { a[i] += 2.0f*k[i];  s[i] = fmaf(dt,  k[i], x[i]); }
    // k4
    DERIV(s, k);
#pragma unroll
    for (int i = 0; i < 20; ++i) { a[i] += k[i]; }

    const float sc = dt * (1.0f / 6.0f);
#pragma unroll
    for (int j = 0; j < 5; ++j) {
        float4 r;
        r.x = fmaf(sc, a[4*j+0], x[4*j+0]);
        r.y = fmaf(sc, a[4*j+1], x[4*j+1]);
        r.z = fmaf(sc, a[4*j+2], x[4*j+2]);
        r.w = fmaf(sc, a[4*j+3], x[4*j+3]);
        out[base + j] = r;
    }
#undef DERIV
}

extern "C" void kernel_launch(void* const* d_in, const int* in_sizes, int n_in,
                              void* d_out, int out_size, void* d_ws, size_t ws_size,
                              hipStream_t stream) {
    const float4* x0 = (const float4*)d_in[0];
    // d_in[1] = t (unused; autonomous system)
    const float* dt = (const float*)d_in[2];
    float4* out = (float4*)d_out;

    const long nhalf = (long)in_sizes[0] / 20;     // batch*2 half-rows
    const int block = 256;
    const long grid = (nhalf + block - 1) / block;
    lorenz96_rk4_dpp<<<dim3((unsigned)grid), dim3(block), 0, stream>>>(x0, dt, out, nhalf);
}

// Round 2
// 149.078 us; speedup vs baseline: 1.0521x; 1.0521x over previous
//
#include <hip/hip_runtime.h>

// Lorenz96 RK4, fp32 — redundant-halo, shuffle-free:
//   Round-0 coalesced layout (10 lanes x 1 float4 per row, 6 rows/wave,
//   lanes 60..63 idle) but NO cross-lane ops at all. RK4's stencil grows
//   (-2,+1) per stage, so a lane's 4 outputs need x over [p-8, p+7] =
//   exactly 4 aligned float4s of its row (cols c-2,c-1,c,c+1 mod 10).
//   Each lane loads those 4 (same 960B wave footprint, mod-10 permuted ->
//   same ~16 cachelines/instr, L1 absorbs the 4x re-read) and computes
//   k1 on 13 els, k2 on 10, k3 on 7, k4 on 4 — pure per-thread ALU.
//   No LDS, no shuffles, no barriers; divergent early-return is safe.

#define FORCE 8.0f

__global__ __launch_bounds__(256)
void lorenz96_rk4_halo(const float4* __restrict__ x0,
                       const float* __restrict__ dt_p,
                       float4* __restrict__ out,
                       long nf4)   // batch * 10 float4s total
{
    const long tid  = (long)blockIdx.x * blockDim.x + threadIdx.x;
    const long wave = tid >> 6;
    const int  lane = (int)(tid & 63);
    const int  lrow = lane / 10;          // row within wave, 0..5 (6 = idle)
    const int  c    = lane - lrow * 10;   // float4 column within row, 0..9
    const long f    = wave * 60 + lane;   // this lane's own float4 index
    if (lane >= 60 || f >= nf4) return;   // whole rows are always complete
                                          // (nf4 % 10 == 0), so active lanes
                                          // never read a truncated row

    const long rowbase = wave * 60 + (long)lrow * 10;
    const int cm2 = (c >= 2) ? c - 2 : c + 8;    // (c-2) mod 10
    const int cm1 = (c >= 1) ? c - 1 : c + 9;    // (c-1) mod 10
    const int cp1 = (c <= 8) ? c + 1 : c - 9;    // (c+1) mod 10

    // x window [p-8, p+7], p = 4c: four aligned float4s, issued back-to-back
    const float4 vm2 = x0[rowbase + cm2];
    const float4 vm1 = x0[rowbase + cm1];
    const float4 v0  = x0[rowbase + c  ];
    const float4 vp1 = x0[rowbase + cp1];

    float xa[16];
    xa[0]=vm2.x; xa[1]=vm2.y; xa[2]=vm2.z; xa[3]=vm2.w;
    xa[4]=vm1.x; xa[5]=vm1.y; xa[6]=vm1.z; xa[7]=vm1.w;
    xa[8]=v0.x;  xa[9]=v0.y;  xa[10]=v0.z; xa[11]=v0.w;
    xa[12]=vp1.x; xa[13]=vp1.y; xa[14]=vp1.z; xa[15]=vp1.w;

    const float dt  = dt_p[0];
    const float hdt = 0.5f * dt;

    // d[i] = (x[i+1] - x[i-2]) * x[i-1] - x[i] + F
    // arrays are window-relative; the deriv pattern is always
    //   D[i] = (S[i+3] - S[i]) * S[i+1] - S[i+2] + F  (window shrinks by 3)

    float k1[13], y1[13];           // positions [p-6, p+6]
#pragma unroll
    for (int i = 0; i < 13; ++i)
        k1[i] = (xa[i+3] - xa[i]) * xa[i+1] - xa[i+2] + FORCE;
#pragma unroll
    for (int i = 0; i < 13; ++i)
        y1[i] = fmaf(hdt, k1[i], xa[i+2]);

    float k2[10], y2[10];           // positions [p-4, p+5]
#pragma unroll
    for (int i = 0; i < 10; ++i)
        k2[i] = (y1[i+3] - y1[i]) * y1[i+1] - y1[i+2] + FORCE;
#pragma unroll
    for (int i = 0; i < 10; ++i)
        y2[i] = fmaf(hdt, k2[i], xa[i+4]);

    float k3[7], y3[7];             // positions [p-2, p+4]
#pragma unroll
    for (int i = 0; i < 7; ++i)
        k3[i] = (y2[i+3] - y2[i]) * y2[i+1] - y2[i+2] + FORCE;
#pragma unroll
    for (int i = 0; i < 7; ++i)
        y3[i] = fmaf(dt, k3[i], xa[i+6]);

    float k4[4];                    // positions [p, p+3]
#pragma unroll
    for (int i = 0; i < 4; ++i)
        k4[i] = (y3[i+3] - y3[i]) * y3[i+1] - y3[i+2] + FORCE;

    // out[m] = x[p+m] + dt/6 * (k1 + 2k2 + 2k3 + k4) at pos p+m
    const float sc = dt * (1.0f / 6.0f);
    float acc[4];
#pragma unroll
    for (int m = 0; m < 4; ++m) {
        float t = k1[m+6] + k4[m];
        t = fmaf(2.0f, k2[m+4], t);
        t = fmaf(2.0f, k3[m+2], t);
        acc[m] = t;
    }
    float4 r;
    r.x = fmaf(sc, acc[0], xa[8]);
    r.y = fmaf(sc, acc[1], xa[9]);
    r.z = fmaf(sc, acc[2], xa[10]);
    r.w = fmaf(sc, acc[3], xa[11]);
    out[f] = r;
}

extern "C" void kernel_launch(void* const* d_in, const int* in_sizes, int n_in,
                              void* d_out, int out_size, void* d_ws, size_t ws_size,
                              hipStream_t stream) {
    const float4* x0 = (const float4*)d_in[0];
    // d_in[1] = t (unused; autonomous system)
    const float* dt = (const float*)d_in[2];
    float4* out = (float4*)d_out;

    const long nf4 = (long)in_sizes[0] / 4;        // batch*10 float4s
    const long nwaves = (nf4 + 59) / 60;           // 60 active f4 per wave
    const int block = 256;                          // 4 waves/block
    const long grid = (nwaves + 3) / 4;
    lorenz96_rk4_halo<<<dim3((unsigned)grid), dim3(block), 0, stream>>>(x0, dt, out, nf4);
}